// Round 4
// baseline (720.973 us; speedup 1.0000x reference)
//
#include <hip/hip_runtime.h>
#include <hip/hip_bf16.h>

#define VOCAB  32000
#define EMBED  32
#define HIDDEN 16
#define SEQ    128
#define BATCH  32

typedef __attribute__((ext_vector_type(8))) short short8;
typedef __attribute__((ext_vector_type(4))) float float4v;

#define LOG2E 1.4426950408889634f
#define LN2   0.6931471805599453f

// vocab tiling for the logits kernels
#define NSLICE 10                  // vocab slices per row-group
#define TPB    200                 // 16-row vocab tiles per block (2000/NSLICE)
#define TPW    25                  // tiles per wave (TPB / 8 waves): 6x4 + 1 tail

__device__ __forceinline__ float fexp2(float x) { return __builtin_amdgcn_exp2f(x); }
__device__ __forceinline__ float frcp(float x)  { return __builtin_amdgcn_rcpf(x); }
__device__ __forceinline__ float flog2(float x) { return __builtin_amdgcn_logf(x); }

// RTNE float -> bf16 bits (finite inputs only)
__device__ __forceinline__ unsigned short f2bf(float x) {
    unsigned u = __float_as_uint(x);
    unsigned r = u + 0x7fffu + ((u >> 16) & 1u);
    return (unsigned short)(r >> 16);
}

// ---------------------------------------------------------------------------
// Kernel 1 (fused front): blocks 0..31 = LSTM recurrence (wave 0 only) with
// ON-THE-FLY input projection (no proj workspace, no k_prep kernel);
// blocks 32..563 = W_out/b_out fp32->bf16 convert; block 564 = zero gsum.
// Convert runs on CUs idle during the serial LSTM.
// ---------------------------------------------------------------------------
__global__ __launch_bounds__(256) void k_mid(
    const int* __restrict__ idx,
    const float* __restrict__ emb,
    const float* __restrict__ W_ih,
    const float* __restrict__ W_hh,
    const float* __restrict__ b_ih,
    const float* __restrict__ b_hh,
    const float* __restrict__ h0,
    const float* __restrict__ c0,
    unsigned short* __restrict__ h_ws,
    const float* __restrict__ W_out,
    const float* __restrict__ b_out,
    unsigned short* __restrict__ Wo16,
    unsigned short* __restrict__ bo16,
    float* __restrict__ gsum)
{
    int bx = blockIdx.x;
    if (bx < 32) {
        if (threadIdx.x >= 64) return;
        int b = bx;
        int j = threadIdx.x;

        // per-lane weights: W_ih row j (32) + W_hh row j (16)
        float wih[32];
        {
            const float4* wp = (const float4*)(W_ih + j * 32);
#pragma unroll
            for (int i = 0; i < 8; ++i) *((float4*)wih + i) = wp[i];
        }
        float whh[16];
        {
            const float4* wp = (const float4*)(W_hh + j * 16);
#pragma unroll
            for (int i = 0; i < 4; ++i) *((float4*)whh + i) = wp[i];
        }
        float bias = b_ih[j] + b_hh[j];

        int l15 = j & 15;
        float h = h0[b * HIDDEN + l15];
        float c = c0[b * HIDDEN + l15];

        // all 128 step-indices for this batch, 2 per lane
        int i0 = idx[j * BATCH + b];
        int i1 = idx[(j + 64) * BATCH + b];

        // double-buffered emb rows: XA = even steps, XB = odd steps
        float XA[32], XB[32];
        {
            int v0 = __builtin_amdgcn_readfirstlane(__shfl(i0, 0));
            const float4* ep = (const float4*)(emb + (size_t)v0 * 32);
#pragma unroll
            for (int i = 0; i < 8; ++i) *((float4*)XA + i) = ep[i];
            int v1 = __builtin_amdgcn_readfirstlane(__shfl(i0, 1));
            const float4* eq = (const float4*)(emb + (size_t)v1 * 32);
#pragma unroll
            for (int i = 0; i < 8; ++i) *((float4*)XB + i) = eq[i];
        }

#define LSTM_STEP(XBUF, s)                                                    \
        {                                                                     \
            /* input projection: 4 parallel chains, hides under shuffles */   \
            float g0 = 0.f, g1 = 0.f, g2 = 0.f, g3 = 0.f;                     \
            _Pragma("unroll")                                                 \
            for (int i = 0; i < 8; ++i) {                                     \
                g0 += XBUF[4*i]   * wih[4*i];                                 \
                g1 += XBUF[4*i+1] * wih[4*i+1];                               \
                g2 += XBUF[4*i+2] * wih[4*i+2];                               \
                g3 += XBUF[4*i+3] * wih[4*i+3];                               \
            }                                                                 \
            float xg = bias + ((g0 + g1) + (g2 + g3));                        \
            /* prefetch emb row for step s+2 into same buffer */              \
            if ((s) + 2 < SEQ) {                                              \
                int sn = (s) + 2;                                             \
                int vn = __shfl((sn < 64) ? i0 : i1, sn & 63);                \
                int vs = __builtin_amdgcn_readfirstlane(vn);                  \
                const float4* ep = (const float4*)(emb + (size_t)vs * 32);    \
                _Pragma("unroll")                                             \
                for (int i = 0; i < 8; ++i) *((float4*)XBUF + i) = ep[i];     \
            }                                                                 \
            float a0 = 0.f, a1 = 0.f;                                         \
            _Pragma("unroll")                                                 \
            for (int k = 0; k < 8; ++k) {                                     \
                a0 += whh[2*k]   * __shfl(h, 2*k);                            \
                a1 += whh[2*k+1] * __shfl(h, 2*k+1);                          \
            }                                                                 \
            float acc = xg + a0 + a1;                                         \
            float e1 = fexp2(-acc * LOG2E);                                   \
            float sg = frcp(1.f + e1);                                        \
            float e2 = fexp2(-2.f * acc * LOG2E);                             \
            float th = 2.f * frcp(1.f + e2) - 1.f;                            \
            float act = ((j >> 4) == 2) ? th : sg;                            \
            float i_ = __shfl(act, l15);                                      \
            float f_ = __shfl(act, l15 + 16);                                 \
            float g_ = __shfl(act, l15 + 32);                                 \
            float o_ = __shfl(act, l15 + 48);                                 \
            c = f_ * c + i_ * g_;                                             \
            float e3 = fexp2(-2.f * c * LOG2E);                               \
            float hc = 2.f * frcp(1.f + e3) - 1.f;                            \
            h = o_ * hc;                                                      \
            if (j < 16)                                                       \
                h_ws[(size_t)((s) * BATCH + b) * HIDDEN + j] = f2bf(h);       \
        }

        for (int s = 0; s < SEQ; s += 2) {
            LSTM_STEP(XA, s)
            LSTM_STEP(XB, s + 1)
        }
#undef LSTM_STEP
    } else if (bx < 564) {
        int t4 = ((bx - 32) * 256 + threadIdx.x) * 4;
        const int NW = VOCAB * HIDDEN;                 // 512000
        if (t4 < NW) {
            float4 v = *(const float4*)(W_out + t4);
            Wo16[t4 + 0] = f2bf(v.x); Wo16[t4 + 1] = f2bf(v.y);
            Wo16[t4 + 2] = f2bf(v.z); Wo16[t4 + 3] = f2bf(v.w);
        } else if (t4 < NW + VOCAB) {
            int j = t4 - NW;
            float4 v = *(const float4*)(b_out + j);
            bo16[j + 0] = f2bf(v.x); bo16[j + 1] = f2bf(v.y);
            bo16[j + 2] = f2bf(v.z); bo16[j + 3] = f2bf(v.w);
        }
    } else {
        for (int i = threadIdx.x; i < 1024; i += 256)
            ((float4*)gsum)[i] = make_float4(0.f, 0.f, 0.f, 0.f);
    }
}

// ---------------------------------------------------------------------------
// Kernel 2: partial log-sum-exp. grid 2560 (rg = bid/NSLICE), 512 thr.
// 4-tile load groups (4 A-loads in flight) + 1 tail tile.
// Logits bounded (|h|<1, |W|,|b|<=0.25): no max-subtraction needed.
// ---------------------------------------------------------------------------
__global__ __launch_bounds__(512, 4) void k_lse(
    const unsigned short* __restrict__ Wo16,
    const unsigned short* __restrict__ bo16,
    const unsigned short* __restrict__ h_ws,
    float* __restrict__ gsum)
{
    __shared__ float sums[8][16];

    int bid  = blockIdx.x;
    int rg   = bid / NSLICE;
    int sl   = bid - rg * NSLICE;
    int r0   = rg * 16;
    int tid  = threadIdx.x;
    int wave = tid >> 6;
    int lane = tid & 63;
    int n = lane & 15;
    int q = lane >> 4;

    short8 bfrag = {0, 0, 0, 0, 0, 0, 0, 0};
    if (q < 2)
        bfrag = *(const short8*)(h_ws + (size_t)(r0 + n) * 16 + 8 * q);
    else if (q == 2)
        bfrag[0] = (short)0x3F80;   // 1.0 bf16 in K-slot 16 (bias row)

    int t0 = sl * TPB + wave * TPW;

    float s0 = 0.f, s1 = 0.f, s2 = 0.f, s3 = 0.f;

    for (int ss = 0; ss < 6; ++ss) {
        int tb = t0 + ss * 4;
        short8 A[4];
#pragma unroll
        for (int t = 0; t < 4; ++t) {
            short8 a = {0, 0, 0, 0, 0, 0, 0, 0};
            int v0 = (tb + t) * 16;
            if (q < 2)       a = *(const short8*)(Wo16 + (size_t)(v0 + n) * 16 + 8 * q);
            else if (q == 2) a[0] = (short)bo16[v0 + n];
            A[t] = a;
        }
#pragma unroll
        for (int t = 0; t < 4; ++t) {
            float4v dz = {0.f, 0.f, 0.f, 0.f};
            float4v d = __builtin_amdgcn_mfma_f32_16x16x32_bf16(A[t], bfrag, dz, 0, 0, 0);
            s0 += fexp2(d[0] * LOG2E);
            s1 += fexp2(d[1] * LOG2E);
            s2 += fexp2(d[2] * LOG2E);
            s3 += fexp2(d[3] * LOG2E);
        }
    }
    {   // tail tile
        int v0 = (t0 + 24) * 16;
        short8 a = {0, 0, 0, 0, 0, 0, 0, 0};
        if (q < 2)       a = *(const short8*)(Wo16 + (size_t)(v0 + n) * 16 + 8 * q);
        else if (q == 2) a[0] = (short)bo16[v0 + n];
        float4v dz = {0.f, 0.f, 0.f, 0.f};
        float4v d = __builtin_amdgcn_mfma_f32_16x16x32_bf16(a, bfrag, dz, 0, 0, 0);
        s0 += fexp2(d[0] * LOG2E);
        s1 += fexp2(d[1] * LOG2E);
        s2 += fexp2(d[2] * LOG2E);
        s3 += fexp2(d[3] * LOG2E);
    }

    float ssum = (s0 + s1) + (s2 + s3);
    ssum += __shfl_xor(ssum, 16);
    ssum += __shfl_xor(ssum, 32);
    if (q == 0) sums[wave][n] = ssum;
    __syncthreads();

    if (tid < 16) {
        float tot = 0.f;
#pragma unroll
        for (int wv = 0; wv < 8; ++wv) tot += sums[wv][tid];
        atomicAdd(&gsum[r0 + tid], tot);   // device-scope, cross-XCD safe
    }
}

// ---------------------------------------------------------------------------
// Kernel 3: recompute logits, subtract ln(gsum), store fp32 NON-TEMPORAL.
// Wave-local LDS transpose (XOR-swizzled): per 4-tile superstep each store
// covers 4 rows x 256 B contiguous (full L2 lines). nt stores keep the
// 524 MB write-once stream from thrashing L2.
// ---------------------------------------------------------------------------
__global__ __launch_bounds__(512, 4) void k_write(
    const unsigned short* __restrict__ Wo16,
    const unsigned short* __restrict__ bo16,
    const unsigned short* __restrict__ h_ws,
    const float* __restrict__ gsum,
    float* __restrict__ out)
{
    __shared__ float lds[8][1024];   // 4 KB per wave (16 rows x 64 vocab fp32)

    int bid  = blockIdx.x;
    int rg   = bid / NSLICE;
    int sl   = bid - rg * NSLICE;
    int r0   = rg * 16;
    int tid  = threadIdx.x;
    int wave = tid >> 6;
    int lane = tid & 63;
    int n = lane & 15;
    int q = lane >> 4;
    float* wl = lds[wave];

    short8 bfrag = {0, 0, 0, 0, 0, 0, 0, 0};
    if (q < 2)
        bfrag = *(const short8*)(h_ws + (size_t)(r0 + n) * 16 + 8 * q);
    else if (q == 2)
        bfrag[0] = (short)0x3F80;

    float K = flog2(gsum[r0 + n]) * LN2;   // ln(sum exp(y)) for row r0+n

    int t0 = sl * TPB + wave * TPW;

    for (int ss = 0; ss < 6; ++ss) {
        int tb = t0 + ss * 4;
        short8 A[4];
#pragma unroll
        for (int t = 0; t < 4; ++t) {
            short8 a = {0, 0, 0, 0, 0, 0, 0, 0};
            int v0 = (tb + t) * 16;
            if (q < 2)       a = *(const short8*)(Wo16 + (size_t)(v0 + n) * 16 + 8 * q);
            else if (q == 2) a[0] = (short)bo16[v0 + n];
            A[t] = a;
        }
        // MFMA + K-subtract + swizzled LDS stage (value = row n, vocab unit u)
#pragma unroll
        for (int t = 0; t < 4; ++t) {
            float4v dz = {0.f, 0.f, 0.f, 0.f};
            float4v d = __builtin_amdgcn_mfma_f32_16x16x32_bf16(A[t], bfrag, dz, 0, 0, 0);
            float4v ov;
            ov[0] = d[0] - K; ov[1] = d[1] - K;
            ov[2] = d[2] - K; ov[3] = d[3] - K;
            int u = t * 4 + q;                       // 16B-unit within 64-vocab tile
            *(float4v*)(wl + (size_t)(n * 16 + (u ^ n)) * 4) = ov;
        }
        // transpose-read + contiguous nt store: instr k = rows 4k+q, unit n
        int V0 = tb * 16;
#pragma unroll
        for (int k = 0; k < 4; ++k) {
            int rr = 4 * k + q;                      // row within rowgroup
            float4v val = *(const float4v*)(wl + (size_t)(rr * 16 + (n ^ rr)) * 4);
            __builtin_nontemporal_store(val,
                (float4v*)(out + (size_t)(r0 + rr) * VOCAB + V0 + n * 4));
        }
    }
    {   // tail tile (direct nt store)
        int v0 = (t0 + 24) * 16;
        short8 a = {0, 0, 0, 0, 0, 0, 0, 0};
        if (q < 2)       a = *(const short8*)(Wo16 + (size_t)(v0 + n) * 16 + 8 * q);
        else if (q == 2) a[0] = (short)bo16[v0 + n];
        float4v dz = {0.f, 0.f, 0.f, 0.f};
        float4v d = __builtin_amdgcn_mfma_f32_16x16x32_bf16(a, bfrag, dz, 0, 0, 0);
        float4v ov;
        ov[0] = d[0] - K; ov[1] = d[1] - K;
        ov[2] = d[2] - K; ov[3] = d[3] - K;
        __builtin_nontemporal_store(ov,
            (float4v*)(out + (size_t)(r0 + n) * VOCAB + v0 + 4 * q));
    }
}

// ---------------------------------------------------------------------------
extern "C" void kernel_launch(void* const* d_in, const int* in_sizes, int n_in,
                              void* d_out, int out_size, void* d_ws, size_t ws_size,
                              hipStream_t stream)
{
    const int*   idx   = (const int*)d_in[0];
    const float* emb   = (const float*)d_in[1];
    const float* W_ih  = (const float*)d_in[2];
    const float* W_hh  = (const float*)d_in[3];
    const float* b_ih  = (const float*)d_in[4];
    const float* b_hh  = (const float*)d_in[5];
    const float* W_out = (const float*)d_in[6];
    const float* b_out = (const float*)d_in[7];
    const float* h0    = (const float*)d_in[8];
    const float* c0    = (const float*)d_in[9];

    // workspace layout:
    //   Wo16  [32000][16] bf16 : 1.024 MB
    //   bo16  [32000]     bf16 : 64 KB
    //   h_ws  [4096][16]  bf16 : 128 KB
    //   gsum  [4096]      fp32 : 16 KB
    char* p = (char*)d_ws;
    unsigned short* Wo16 = (unsigned short*)p;             p += (size_t)VOCAB * 16 * 2;
    unsigned short* bo16 = (unsigned short*)p;             p += (size_t)VOCAB * 2;
    unsigned short* h_ws = (unsigned short*)p;             p += (size_t)SEQ * BATCH * HIDDEN * 2;
    float*          gsum = (float*)p;

    k_mid<<<565, 256, 0, stream>>>(idx, emb, W_ih, W_hh, b_ih, b_hh, h0, c0,
                                   h_ws, W_out, b_out, Wo16, bo16, gsum);
    k_lse<<<SEQ * BATCH / 16 * NSLICE, 512, 0, stream>>>(Wo16, bo16, h_ws, gsum);
    k_write<<<SEQ * BATCH / 16 * NSLICE, 512, 0, stream>>>(Wo16, bo16, h_ws, gsum,
                                                           (float*)d_out);
}